// Round 2
// baseline (165.207 us; speedup 1.0000x reference)
//
#include <hip/hip_runtime.h>
#include <math.h>

// NeRF ray-march forward (MipRayMarcher2), thread-per-ray.
// B=4, R=65536, S=48 -> nRays = 262144 rays, 47 intervals each.
// Outputs flat: rgb [nRays*3], depth [nRays], weights [nRays*47].

#define S_SAMPLES 48
#define S_INTERVALS 47
#define CS 8          // samples per chunk
#define NCHUNK 6      // 48 / CS

__device__ __forceinline__ unsigned f2u_sortable(float f) {
    unsigned u = __float_as_uint(f);
    return (u & 0x80000000u) ? ~u : (u | 0x80000000u);
}
__device__ __forceinline__ float u2f_sortable(unsigned u) {
    return (u & 0x80000000u) ? __uint_as_float(u ^ 0x80000000u)
                             : __uint_as_float(~u);
}

__global__ void init_ws_kernel(unsigned* ws) {
    ws[0] = 0xFFFFFFFFu;  // min identity
    ws[1] = 0u;           // max identity
}

__global__ __launch_bounds__(256) void raymarch_kernel(
    const float* __restrict__ colors,     // [nRays, 48, 3]
    const float* __restrict__ densities,  // [nRays, 48]
    const float* __restrict__ depths,     // [nRays, 48]
    unsigned* __restrict__ ws,            // out: sortable-uint gmin/gmax
    float* __restrict__ out_rgb,          // [nRays, 3]
    float* __restrict__ out_depth,        // [nRays] (unclamped here)
    float* __restrict__ out_w,            // [nRays, 47]
    int nRays) {
    const int ray = blockIdx.x * blockDim.x + threadIdx.x;

    float mnd = INFINITY, mxd = -INFINITY;

    if (ray < nRays) {
        const float4* dp = (const float4*)(depths + (size_t)ray * S_SAMPLES);
        const float4* np = (const float4*)(densities + (size_t)ray * S_SAMPLES);
        const float4* cp = (const float4*)(colors + (size_t)ray * (S_SAMPLES * 3));
        float* wp = out_w + (size_t)ray * S_INTERVALS;

        float T = 1.f;
        float s0 = 0.f, s1 = 0.f, s2 = 0.f, sw = 0.f, sd = 0.f;
        float pDep = 0.f, pDen = 0.f, pC0 = 0.f, pC1 = 0.f, pC2 = 0.f;

        for (int ch = 0; ch < NCHUNK; ++ch) {
            // ---- load 8 samples: 2 + 2 + 6 float4 ----
            float4 dv0 = dp[ch * 2 + 0], dv1 = dp[ch * 2 + 1];
            float4 nv0 = np[ch * 2 + 0], nv1 = np[ch * 2 + 1];
            float4 cv0 = cp[ch * 6 + 0], cv1 = cp[ch * 6 + 1], cv2 = cp[ch * 6 + 2];
            float4 cv3 = cp[ch * 6 + 3], cv4 = cp[ch * 6 + 4], cv5 = cp[ch * 6 + 5];

            float dep[CS] = {dv0.x, dv0.y, dv0.z, dv0.w, dv1.x, dv1.y, dv1.z, dv1.w};
            float den[CS] = {nv0.x, nv0.y, nv0.z, nv0.w, nv1.x, nv1.y, nv1.z, nv1.w};
            float cc[CS * 3] = {cv0.x, cv0.y, cv0.z, cv0.w, cv1.x, cv1.y, cv1.z, cv1.w,
                                cv2.x, cv2.y, cv2.z, cv2.w, cv3.x, cv3.y, cv3.z, cv3.w,
                                cv4.x, cv4.y, cv4.z, cv4.w, cv5.x, cv5.y, cv5.z, cv5.w};

            if (ch == 0) mnd = dep[0];
            if (ch == NCHUNK - 1) mxd = dep[CS - 1];

#pragma unroll
            for (int s = 0; s < CS; ++s) {
                const int g = ch * CS + s;  // global sample index of "current"
                if (g > 0) {
                    // interval k = g-1 between prev sample and this one
                    float delta = dep[s] - pDep;
                    float dm = 0.5f * (dep[s] + pDep);
                    float denm = 0.5f * (den[s] + pDen) - 1.f;
                    // stable softplus
                    float sp = fmaxf(denm, 0.f) + log1pf(expf(-fabsf(denm)));
                    float alpha = 1.f - expf(-sp * delta);
                    float w = alpha * T;
                    T *= (1.f - alpha + 1e-10f);
                    s0 = fmaf(w, 0.5f * (cc[s * 3 + 0] + pC0), s0);
                    s1 = fmaf(w, 0.5f * (cc[s * 3 + 1] + pC1), s1);
                    s2 = fmaf(w, 0.5f * (cc[s * 3 + 2] + pC2), s2);
                    sw += w;
                    sd = fmaf(w, dm, sd);
                    wp[g - 1] = w;
                }
                pDep = dep[s];
                pDen = den[s];
                pC0 = cc[s * 3 + 0];
                pC1 = cc[s * 3 + 1];
                pC2 = cc[s * 3 + 2];
            }
        }

        size_t rb = (size_t)ray * 3;
        out_rgb[rb + 0] = fmaf(s0, 2.f, -1.f);
        out_rgb[rb + 1] = fmaf(s1, 2.f, -1.f);
        out_rgb[rb + 2] = fmaf(s2, 2.f, -1.f);
        out_depth[ray] = sd / sw;  // NaN handled in clamp pass
    }

    // ---- fused global depth min/max: wave reduce -> block reduce -> atomic ----
    const int lane = threadIdx.x & 63;
    const int wid = threadIdx.x >> 6;
#pragma unroll
    for (int off = 32; off; off >>= 1) {
        mnd = fminf(mnd, __shfl_xor(mnd, off));
        mxd = fmaxf(mxd, __shfl_xor(mxd, off));
    }
    __shared__ float smn[4], smx[4];
    if (lane == 0) {
        smn[wid] = mnd;
        smx[wid] = mxd;
    }
    __syncthreads();
    if (threadIdx.x == 0) {
        float m = fminf(fminf(smn[0], smn[1]), fminf(smn[2], smn[3]));
        float M = fmaxf(fmaxf(smx[0], smx[1]), fmaxf(smx[2], smx[3]));
        atomicMin(&ws[0], f2u_sortable(m));
        atomicMax(&ws[1], f2u_sortable(M));
    }
}

__global__ __launch_bounds__(256) void clamp_depth_kernel(
    float* __restrict__ out_depth, const unsigned* __restrict__ ws, int n) {
    int i = blockIdx.x * blockDim.x + threadIdx.x;
    if (i < n) {
        float gmin = u2f_sortable(ws[0]);
        float gmax = u2f_sortable(ws[1]);
        float d = out_depth[i];
        if (isnan(d)) d = INFINITY;  // nan_to_num(nan=inf)
        d = fminf(fmaxf(d, gmin), gmax);
        out_depth[i] = d;
    }
}

extern "C" void kernel_launch(void* const* d_in, const int* in_sizes, int n_in,
                              void* d_out, int out_size, void* d_ws, size_t ws_size,
                              hipStream_t stream) {
    const float* colors = (const float*)d_in[0];
    const float* densities = (const float*)d_in[1];
    const float* depths = (const float*)d_in[2];

    const int nRays = in_sizes[2] / S_SAMPLES;  // 262144

    float* out = (float*)d_out;
    float* out_rgb = out;                        // nRays*3
    float* out_depth = out + (size_t)nRays * 3;  // nRays
    float* out_w = out + (size_t)nRays * 4;      // nRays*47

    unsigned* ws = (unsigned*)d_ws;

    init_ws_kernel<<<1, 1, 0, stream>>>(ws);

    const int nBlocks = (nRays + 255) / 256;
    raymarch_kernel<<<nBlocks, 256, 0, stream>>>(
        colors, densities, depths, ws, out_rgb, out_depth, out_w, nRays);
    clamp_depth_kernel<<<nBlocks, 256, 0, stream>>>(out_depth, ws, nRays);
}